// Round 3
// baseline (417.963 us; speedup 1.0000x reference)
//
#include <hip/hip_runtime.h>
#include <stdint.h>

#define H 4096
#define KSEL 410
#define NT 256
#define FAST_MAX 256u

typedef uint32_t u32x4 __attribute__((ext_vector_type(4)));

__device__ __forceinline__ uint32_t absbits(float f) {
  return __float_as_uint(f) & 0x7fffffffu;
}

// Generic MSB-first radix-select round (fallback path only), reading abs-bits
// on the fly from the register-held row data r[4] (16 values per thread).
template <int SHIFT, int WIDTH, int LOG_PER, bool CLEAR, bool UNCOND>
__device__ __forceinline__ void select_round(
    const u32x4* __restrict__ r,
    uint32_t* hist, uint32_t* aux,
    uint32_t* s_bin, uint32_t* s_k, uint32_t* s_cnt,
    uint32_t& prefix, uint32_t& k, const int tid) {
  constexpr int NB = 1 << WIDTH;
  constexpr int PER = NB / NT;
  static_assert(PER == (1 << LOG_PER), "per mismatch");
  constexpr int HI = SHIFT + WIDTH;                  // bits above this field
  constexpr int PSIZE = NB + (NB >> LOG_PER);        // padded layout size

  if (CLEAR) {
    for (int b = tid; b < PSIZE; b += NT) hist[b] = 0;
    __syncthreads();
  }

  #pragma unroll
  for (int jv = 0; jv < 4; ++jv) {
    #pragma unroll
    for (int c = 0; c < 4; ++c) {
      const uint32_t uj = r[jv][c] & 0x7fffffffu;
      if (UNCOND || (uj >> HI) == prefix) {
        const uint32_t b = (uj >> SHIFT) & (NB - 1);
        atomicAdd(&hist[b + (b >> LOG_PER)], 1u);    // padded: conflict-spread
      }
    }
  }
  __syncthreads();

  // local suffix sums over my PER contiguous bins (stride PER+1 -> no bank conflicts)
  uint32_t loc[PER];
  {
    uint32_t sum = 0;
    #pragma unroll
    for (int j = PER - 1; j >= 0; --j) {
      sum += hist[tid * (PER + 1) + j];
      loc[j] = sum;
    }
    aux[tid] = sum;
  }
  __syncthreads();

  // wave 0: replace aux[t] with sum over all t' > t (suffix-exclusive)
  if (tid < 64) {
    uint4 a = ((const uint4*)aux)[tid];
    const uint32_t lsum = a.x + a.y + a.z + a.w;
    uint32_t s = lsum;
    #pragma unroll
    for (int off = 1; off < 64; off <<= 1) {
      uint32_t t = __shfl_down(s, off, 64);
      if (tid + off < 64) s += t;
    }
    const uint32_t above = s - lsum;                 // strictly-above lanes
    uint4 o;
    o.x = above + a.y + a.z + a.w;
    o.y = above + a.z + a.w;
    o.z = above + a.w;
    o.w = above;
    ((uint4*)aux)[tid] = o;
  }
  __syncthreads();

  // find the bin whose suffix range crosses rank k (exactly one thread hits)
  {
    const uint32_t above_t = aux[tid];
    #pragma unroll
    for (int j = 0; j < PER; ++j) {
      const uint32_t s_incl = above_t + loc[j];
      const uint32_t s_abv = (j + 1 < PER) ? (above_t + loc[j + 1]) : above_t;
      if (s_incl >= k && s_abv < k) {
        *s_bin = (uint32_t)(tid * PER + j);
        *s_k = k - s_abv;
        *s_cnt = s_incl - s_abv;                     // size of selected class
      }
    }
  }
  __syncthreads();
  prefix = (prefix << WIDTH) | *s_bin;
  k = *s_k;
}

__global__ __launch_bounds__(NT) void topk_select_kernel(
    const float* __restrict__ x, float* __restrict__ out) {
  __shared__ alignas(16) uint32_t hist[2304];  // 2048 bins padded (+fallback)
  __shared__ alignas(16) uint32_t cand[260];   // fast-path candidates (+pad)
  __shared__ uint32_t aux[NT];
  __shared__ uint32_t s_bin, s_k, s_cnt, s_tb;

  const int tid = threadIdx.x;
  const size_t base = (size_t)blockIdx.x * H;
  const u32x4* __restrict__ xr = (const u32x4*)(x + base);

  // coalesced streaming load: thread t owns vec4s {t, t+256, t+512, t+768}
  u32x4 r[4];
  #pragma unroll
  for (int j = 0; j < 4; ++j) r[j] = __builtin_nontemporal_load(&xr[tid + j * NT]);

  // vectorized clear of round-1 histogram (overlaps load latency)
  {
    const u32x4 z = {0u, 0u, 0u, 0u};
    for (int b4 = tid; b4 < 576; b4 += NT) ((u32x4*)hist)[b4] = z;
  }
  __syncthreads();

  // ---- Round 1 (inlined): top 11 abs-bits, unconditional (bit31 == 0). ----
  // ds_add_rtn gives each element its arrival rank WITHIN its bin for free:
  // ranks in the eventual target bin are a perfect 0..cnt-1 slot assignment,
  // eliminating the gather's serialized single-address atomics entirely.
  uint32_t rk[8];                    // 16 ranks packed 2x16-bit (fit: <=4096)
  #pragma unroll
  for (int j = 0; j < 8; ++j) rk[j] = 0;
  #pragma unroll
  for (int jv = 0; jv < 4; ++jv) {
    #pragma unroll
    for (int c = 0; c < 4; ++c) {
      const int j = jv * 4 + c;
      const uint32_t uj = r[jv][c] & 0x7fffffffu;
      const uint32_t b = uj >> 20;                   // 11 bits
      const uint32_t rr = atomicAdd(&hist[b + (b >> 3)], 1u);
      rk[j >> 1] |= rr << ((j & 1) * 16);
    }
  }
  __syncthreads();

  // local suffix sums over my 8 bins (stride 9 -> conflict-free)
  uint32_t loc[8];
  {
    uint32_t sum = 0;
    #pragma unroll
    for (int j = 7; j >= 0; --j) {
      sum += hist[tid * 9 + j];
      loc[j] = sum;
    }
    aux[tid] = sum;
  }
  __syncthreads();

  if (tid < 64) {                    // wave 0: suffix-exclusive scan of aux
    uint4 a = ((const uint4*)aux)[tid];
    const uint32_t lsum = a.x + a.y + a.z + a.w;
    uint32_t s = lsum;
    #pragma unroll
    for (int off = 1; off < 64; off <<= 1) {
      uint32_t t = __shfl_down(s, off, 64);
      if (tid + off < 64) s += t;
    }
    const uint32_t above = s - lsum;
    uint4 o;
    o.x = above + a.y + a.z + a.w;
    o.y = above + a.z + a.w;
    o.z = above + a.w;
    o.w = above;
    ((uint4*)aux)[tid] = o;
  }
  __syncthreads();

  {
    const uint32_t above_t = aux[tid];
    uint32_t kk = KSEL;
    #pragma unroll
    for (int j = 0; j < 8; ++j) {
      const uint32_t s_incl = above_t + loc[j];
      const uint32_t s_abv = (j + 1 < 8) ? (above_t + loc[j + 1]) : above_t;
      if (s_incl >= kk && s_abv < kk) {
        s_bin = (uint32_t)(tid * 8 + j);
        s_k = kk - s_abv;
        s_cnt = s_incl - s_abv;
      }
    }
  }
  __syncthreads();

  uint32_t prefix = s_bin, k = s_k;
  const uint32_t cnt1 = s_cnt;       // class size after 11 bits (E ~ 100)

  uint32_t tbits, keep_eq, cnt_eq;

  if (cnt1 <= FAST_MAX) {
    // FAST PATH: slot-write candidates via saved ranks (conflict-free, no
    // atomics), then exact O(n^2) rank with vectorized LDS broadcast reads.
    #pragma unroll
    for (int jv = 0; jv < 4; ++jv) {
      #pragma unroll
      for (int c = 0; c < 4; ++c) {
        const int j = jv * 4 + c;
        const uint32_t uj = r[jv][c] & 0x7fffffffu;
        if ((uj >> 20) == prefix) {
          const uint32_t rr = (rk[j >> 1] >> ((j & 1) * 16)) & 0xffffu;
          cand[rr] = uj;
        }
      }
    }
    if (tid < 3) cand[cnt1 + tid] = 0;   // zero-pad for uint4 tail
    __syncthreads();

    const uint32_t n = cnt1;
    const uint32_t n4 = (n + 3) >> 2;
    const uint32_t myv = ((uint32_t)tid < n) ? cand[tid] : 0u;
    uint32_t g = 0, e = 0;
    for (uint32_t i = 0; i < n4; ++i) {  // ~25 ds_read_b128 broadcasts
      const u32x4 cv = ((const u32x4*)cand)[i];
      #pragma unroll
      for (int c = 0; c < 4; ++c) {
        g += (cv[c] > myv) ? 1u : 0u;
        e += (cv[c] == myv) ? 1u : 0u;
      }
    }
    // target class: g < k <= g+e (equal-valued lanes write identical data);
    // pad zeros can't hit: fast path implies prefix > 0 -> myv >= 2^20.
    if ((uint32_t)tid < n && g < k && k <= g + e) {
      s_tb = myv;
      s_k = k - g;
      s_cnt = e;
    }
    __syncthreads();
    tbits = s_tb; keep_eq = s_k; cnt_eq = s_cnt;
  } else {
    // rare: huge tie class at 11 bits -> two more full radix rounds
    select_round<10, 10, 2, true, false>(r, hist, aux, &s_bin, &s_k, &s_cnt, prefix, k, tid);
    select_round< 0, 10, 2, true, false>(r, hist, aux, &s_bin, &s_k, &s_cnt, prefix, k, tid);
    tbits = prefix; keep_eq = k; cnt_eq = s_cnt;
  }

  uint32_t cut = H;                  // default: keep every equal element
  if (cnt_eq != keep_eq) {
    // rare exact tie at the boundary: find index of the keep_eq-th equal
    __syncthreads();                 // drain prior s_* readers
    if (tid == 0) {
      const float* xs = x + base;
      uint32_t c = 0, ct = H;
      for (int i = 0; i < H; ++i) {
        if (absbits(xs[i]) == tbits) {
          if (++c == keep_eq) { ct = (uint32_t)i; break; }
        }
      }
      s_bin = ct;
    }
    __syncthreads();
    cut = s_bin;
  }

  u32x4* __restrict__ outr = (u32x4*)(out + base);
  #pragma unroll
  for (int j = 0; j < 4; ++j) {
    const uint32_t i0 = 4u * (uint32_t)(tid + j * NT);
    u32x4 o;
    #pragma unroll
    for (int c = 0; c < 4; ++c) {
      const uint32_t ub = r[j][c] & 0x7fffffffu;
      const bool keep = (ub > tbits) || (ub == tbits && (i0 + (uint32_t)c) <= cut);
      o[c] = keep ? r[j][c] : 0u;    // zero float == zero bits
    }
    __builtin_nontemporal_store(o, &outr[tid + j * NT]);
  }
}

extern "C" void kernel_launch(void* const* d_in, const int* in_sizes, int n_in,
                              void* d_out, int out_size, void* d_ws, size_t ws_size,
                              hipStream_t stream) {
  const float* x = (const float*)d_in[0];
  float* out = (float*)d_out;
  const int rows = in_sizes[0] / H;   // 16384
  hipLaunchKernelGGL(topk_select_kernel, dim3(rows), dim3(NT), 0, stream, x, out);
}